// Round 2
// baseline (11114.146 us; speedup 1.0000x reference)
//
#include <hip/hip_runtime.h>
#include <hip/hip_bf16.h>
#include <stdint.h>

// Problem constants (fixed by the reference): T=512, B=64, IN=H=1024, L=2
#define TT 512
#define BB 64
#define HH 1024
#define BH 65536    // B*H elements
#define KD 2048     // IN+H == H+H

typedef __attribute__((ext_vector_type(8))) short short8;
typedef __attribute__((ext_vector_type(4))) float f32x4;

__device__ __forceinline__ unsigned short f2bf(float f) {
  union { float f; unsigned int u; } v; v.f = f;
  unsigned int r = v.u + 0x7fffu + ((v.u >> 16) & 1u);  // RNE
  return (unsigned short)(r >> 16);
}
__device__ __forceinline__ float fsig(float x)  { return 1.0f / (1.0f + __expf(-x)); }
__device__ __forceinline__ float ftanhf(float x){ return 1.0f - 2.0f / (__expf(2.0f * x) + 1.0f); }

// ---------------- x -> bf16 ----------------
__global__ void cvt_x_kernel(const float* __restrict__ x, unsigned short* __restrict__ xbf) {
  const int n4 = (TT * BB * 1024) / 4;
  int stride = gridDim.x * blockDim.x;
  for (int i = blockIdx.x * blockDim.x + threadIdx.x; i < n4; i += stride) {
    float4 v = ((const float4*)x)[i];
    unsigned long long p = (unsigned long long)f2bf(v.x)
        | ((unsigned long long)f2bf(v.y) << 16)
        | ((unsigned long long)f2bf(v.z) << 32)
        | ((unsigned long long)f2bf(v.w) << 48);
    ((unsigned long long*)xbf)[i] = p;
  }
}

// ---------------- W [4096][2048] f32 -> bf16 slices [256][16][2048] ----------------
// slice g, row r (r>>2 = gate q, r&3 = local col) <- W[q*1024 + g*4 + (r&3)][:]
__global__ void cvt_w_kernel(const float* __restrict__ W, unsigned short* __restrict__ Ws) {
  int idx = blockIdx.x * blockDim.x + threadIdx.x;   // < 4096*512
  int k4 = idx & 511;
  int r  = (idx >> 9) & 15;
  int g  = idx >> 13;
  int grow = ((r >> 2) << 10) + (g << 2) + (r & 3);
  float4 v = ((const float4*)(W + (size_t)grow * KD))[k4];
  unsigned long long p = (unsigned long long)f2bf(v.x)
      | ((unsigned long long)f2bf(v.y) << 16)
      | ((unsigned long long)f2bf(v.z) << 32)
      | ((unsigned long long)f2bf(v.w) << 48);
  ((unsigned long long*)(Ws + (((size_t)(g * 16 + r)) << 11)))[k4] = p;
}

// ---------------- initial state ----------------
__global__ void init_state_kernel(const float* __restrict__ h0in, const float* __restrict__ c0in,
                                  unsigned short* h0bf, unsigned short* h1bf,
                                  float* h0f32, float* c0f, float* c1f) {
  int i = blockIdx.x * blockDim.x + threadIdx.x;  // < BH
  float a = h0in[i], b = h0in[BH + i];
  h0bf[i] = f2bf(a);
  h1bf[i] = f2bf(b);
  h0f32[i] = a;
  c0f[i] = c0in[i];
  c1f[i] = c0in[BH + i];
}

// ---------------- fused LSTM cell step (pipelined: blocks 0-255 = layer0@t, 256-511 = layer1@t-1) ----
__global__ __launch_bounds__(256) void lstm_step_kernel(
    const unsigned short* __restrict__ W0s, const unsigned short* __restrict__ W1s,
    const float* __restrict__ b0, const float* __restrict__ b1,
    const unsigned short* __restrict__ xbf,
    unsigned short* h0bf, unsigned short* h1bf,
    float* c0f, float* c1f, float* h0f32, float* out, int t)
{
  __shared__ unsigned short wlds[16 * KD];   // 64 KB, XOR-swizzled storage
  const int tid = threadIdx.x;
  const int layer = blockIdx.x >> 8;
  const int g = blockIdx.x & 255;

  const unsigned short *Ws, *in0, *in1;
  const float *bias;
  float *cbuf, *hf;
  unsigned short *hb;
  if (layer == 0) {
    if (t >= TT) return;
    Ws = W0s; bias = b0;
    in0 = xbf + (size_t)t * BH;            // x_t  [64][1024] bf16
    in1 = h0bf + ((t & 1) << 16);          // h0[t-1]
    cbuf = c0f;
    hb = h0bf + (((t & 1) ^ 1) << 16);     // h0[t]
    hf = h0f32;
  } else {
    if (t == 0) return;
    int u = t - 1;
    Ws = W1s; bias = b1;
    in0 = h0bf + (((u & 1) ^ 1) << 16);    // h0[u]  (written by L0 at launch u)
    in1 = h1bf + ((u & 1) << 16);          // h1[u-1]
    cbuf = c1f;
    hb = h1bf + (((u & 1) ^ 1) << 16);     // h1[u]
    hf = out + (size_t)u * BH;             // hlast[u]  (fp32, straight to d_out)
  }

  // ---- stage weight slice [16][2048] bf16 into LDS, swizzled on the write side ----
  {
    const unsigned short* wsrc = Ws + ((size_t)g << 15);  // g*16*2048
    int r   = tid >> 4;          // 0..15 row
    int sub = tid & 15;
    int swz = (r & 7) << 4;
#pragma unroll
    for (int it = 0; it < 16; it++) {
      int cbyte = (sub + it * 16) << 4;  // 16B chunk within row
      short8 v = *(const short8*)((const char*)wsrc + r * 4096 + cbyte);
      *(short8*)((char*)wlds + r * 4096 + (cbyte ^ swz)) = v;
    }
  }
  __syncthreads();

  // ---- MFMA: gates[m, n] = sum_k in[m,k] * Wslice[n,k], M=16/wave, N=16, K=2048 ----
  const int lane = tid & 63;
  const int wv = tid >> 6;        // 0..3 -> batch tile
  const int n  = lane & 15;       // B col == D col == slice row
  const int hi = lane >> 4;       // 0..3
  const int m0 = wv << 4;

  const unsigned short* arow0 = in0 + ((size_t)(m0 + n) << 10) + (hi << 3);
  const unsigned short* arow1 = in1 + ((size_t)(m0 + n) << 10) + (hi << 3);
  const char* brow = (const char*)wlds + (n << 12);
  const int bswz = (n & 7) << 4;

  f32x4 acc = {0.0f, 0.0f, 0.0f, 0.0f};
#pragma unroll 8
  for (int kk = 0; kk < 32; kk++) {
    short8 av = *(const short8*)(arow0 + (kk << 5));
    short8 bv = *(const short8*)(brow + (((kk << 6) + (hi << 4)) ^ bswz));
    acc = __builtin_amdgcn_mfma_f32_16x16x32_bf16(av, bv, acc, 0, 0, 0);
  }
#pragma unroll 8
  for (int kk = 0; kk < 32; kk++) {
    short8 av = *(const short8*)(arow1 + (kk << 5));
    short8 bv = *(const short8*)(brow + ((2048 + (kk << 6) + (hi << 4)) ^ bswz));
    acc = __builtin_amdgcn_mfma_f32_16x16x32_bf16(av, bv, acc, 0, 0, 0);
  }

  // ---- fused gate nonlinearity + state update ----
  // lane holds gates[m = m0 + hi*4 + r][n]; slice row n -> gate q=n>>2, h-col jl=n&3
  int jl = n & 3;
  int jg = (g << 2) + jl;
  float bi = bias[jg], bfv = bias[1024 + jg], bgv = bias[2048 + jg], bov = bias[3072 + jg];
#pragma unroll
  for (int r = 0; r < 4; r++) {
    int src = (lane & 48) | jl;
    float vi = __shfl(acc[r], src,      64);
    float vf = __shfl(acc[r], src | 4,  64);
    float vg = __shfl(acc[r], src | 8,  64);
    float vo = __shfl(acc[r], src | 12, 64);
    if (n < 4) {
      int m = m0 + (hi << 2) + r;
      int idx = (m << 10) + jg;
      float ig = fsig(vi + bi);
      float fg = fsig(vf + bfv);
      float gg = ftanhf(vg + bgv);
      float og = fsig(vo + bov);
      float cn = ig * gg + fg * cbuf[idx];
      float hn = og * ftanhf(cn);
      cbuf[idx] = cn;
      hf[idx] = hn;
      hb[idx] = f2bf(hn);
    }
  }
}

// ---------------- final state copy into d_out tail ----------------
__global__ void final_copy_kernel(const float* __restrict__ h0f32, const float* __restrict__ c0f,
                                  const float* __restrict__ c1f, float* out) {
  int i = blockIdx.x * blockDim.x + threadIdx.x;  // < BH
  const size_t base = (size_t)TT * BH;
  out[base + i]          = h0f32[i];                       // final h, layer 0
  out[base + BH + i]     = out[(size_t)(TT - 1) * BH + i]; // final h, layer 1 == hlast[T-1]
  out[base + 2 * BH + i] = c0f[i];                         // final c, layer 0
  out[base + 3 * BH + i] = c1f[i];                         // final c, layer 1
}

extern "C" void kernel_launch(void* const* d_in, const int* in_sizes, int n_in,
                              void* d_out, int out_size, void* d_ws, size_t ws_size,
                              hipStream_t stream) {
  (void)in_sizes; (void)n_in; (void)out_size; (void)ws_size;
  const float* x    = (const float*)d_in[0];
  const float* h0in = (const float*)d_in[1];
  const float* c0in = (const float*)d_in[2];
  const float* W0   = (const float*)d_in[3];
  const float* b0   = (const float*)d_in[4];
  const float* W1   = (const float*)d_in[5];
  const float* b1   = (const float*)d_in[6];
  float* out = (float*)d_out;

  char* ws = (char*)d_ws;
  unsigned short* Xbf  = (unsigned short*)(ws);                 // 64 MB
  unsigned short* W0s  = (unsigned short*)(ws + 67108864);      // 16 MB
  unsigned short* W1s  = (unsigned short*)(ws + 83886080);      // 16 MB
  unsigned short* h0bf = (unsigned short*)(ws + 100663296);     // 2*128KB
  unsigned short* h1bf = (unsigned short*)(ws + 100925440);     // 2*128KB
  float* h0f32 = (float*)(ws + 101187584);                      // 256KB
  float* c0f   = (float*)(ws + 101449728);                      // 256KB
  float* c1f   = (float*)(ws + 101711872);                      // 256KB

  cvt_x_kernel<<<2048, 256, 0, stream>>>(x, Xbf);
  cvt_w_kernel<<<8192, 256, 0, stream>>>(W0, W0s);
  cvt_w_kernel<<<8192, 256, 0, stream>>>(W1, W1s);
  init_state_kernel<<<256, 256, 0, stream>>>(h0in, c0in, h0bf, h1bf, h0f32, c0f, c1f);

  for (int t = 0; t <= TT; t++) {
    lstm_step_kernel<<<512, 256, 0, stream>>>(W0s, W1s, b0, b1, Xbf,
                                              h0bf, h1bf, c0f, c1f, h0f32, out, t);
  }
  final_copy_kernel<<<256, 256, 0, stream>>>(h0f32, c0f, c1f, out);
}